// Round 2
// baseline (772.355 us; speedup 1.0000x reference)
//
#include <hip/hip_runtime.h>
#include <stdint.h>

typedef unsigned short u16;
typedef __attribute__((ext_vector_type(8))) short short8;
typedef __attribute__((ext_vector_type(4))) float floatx4;

#define D_IN  512
#define M_TOT 24000
#define M_PAD 24064   // 188 * 128
#define V_DIM 4000
#define V_PAD 4096    // 32 * 128
#define T_DIM 150
#define U_DIM 40

__device__ __forceinline__ u16 f2bf(float f) {
    union { float f; uint32_t u; } v; v.f = f;
    uint32_t r = v.u + 0x7FFF + ((v.u >> 16) & 1);   // RNE
    return (u16)(r >> 16);
}

__device__ __forceinline__ void gld_lds16(const u16* g, u16* l) {
    __builtin_amdgcn_global_load_lds(
        (const __attribute__((address_space(1))) void*)g,
        (__attribute__((address_space(3))) void*)l,
        16, 0, 0);
}

// ---------------------------------------------------------------------------
// Kernel 1: enc = enc_state @ W_enc^T + b_enc   [600,512]
//           dec = dec_state @ W_prd^T + b_prd   [160,512]
//           (also zero-inits sumexp accumulator)
// grid (8, 24): x = N-tile (64 cols), y<19 enc M-tiles (32 rows), y>=19 dec
// ---------------------------------------------------------------------------
__global__ void k_pre(const float* __restrict__ enc_state, const float* __restrict__ dec_state,
                      const float* __restrict__ W_enc, const float* __restrict__ b_enc,
                      const float* __restrict__ W_prd, const float* __restrict__ b_prd,
                      float* __restrict__ enc_o, float* __restrict__ dec_o,
                      float* __restrict__ sumexp)
{
    int gid = (blockIdx.y * gridDim.x + blockIdx.x) * blockDim.x + threadIdx.x;
    if (gid < M_TOT) sumexp[gid] = 0.f;

    const float* Ag; const float* Wg; const float* bg; float* Og; int M;
    int by = blockIdx.y;
    if (by < 19) { Ag = enc_state; Wg = W_enc; bg = b_enc; Og = enc_o; M = 600; }
    else         { Ag = dec_state; Wg = W_prd; bg = b_prd; Og = dec_o; M = 160; by -= 19; }

    const int row0 = by * 32;
    const int col0 = blockIdx.x * 64;
    __shared__ float Ash[32][17];   // +1 pad breaks bank conflicts
    __shared__ float Bsh[64][17];
    const int tid = threadIdx.x;
    const int tr = tid & 31;        // output row in tile
    const int tc = tid >> 5;        // 0..7 -> 8 cols each
    float accv[8] = {0.f,0.f,0.f,0.f,0.f,0.f,0.f,0.f};

    for (int k0 = 0; k0 < D_IN; k0 += 16) {
        __syncthreads();
        #pragma unroll
        for (int s = 0; s < 2; ++s) {            // A tile 32x16
            int idx = tid + s * 256;
            int r = idx >> 4, c = idx & 15;
            Ash[r][c] = (row0 + r < M) ? Ag[(size_t)(row0 + r) * D_IN + k0 + c] : 0.f;
        }
        #pragma unroll
        for (int s = 0; s < 4; ++s) {            // B tile 64x16 (W is [512,512])
            int idx = tid + s * 256;
            int r = idx >> 4, c = idx & 15;
            Bsh[r][c] = Wg[(size_t)(col0 + r) * D_IN + k0 + c];
        }
        __syncthreads();
        #pragma unroll
        for (int kk = 0; kk < 16; ++kk) {
            float a = Ash[tr][kk];
            #pragma unroll
            for (int j = 0; j < 8; ++j) accv[j] += a * Bsh[tc * 8 + j][kk];
        }
    }
    if (row0 + tr < M) {
        #pragma unroll
        for (int j = 0; j < 8; ++j)
            Og[(size_t)(row0 + tr) * D_IN + col0 + tc * 8 + j] = accv[j] + bg[col0 + tc * 8 + j];
    }
}

// ---------------------------------------------------------------------------
// Kernel 2: W_proj [4000,512] fp32 -> bf16 [4096,512], zero pad rows
// ---------------------------------------------------------------------------
__global__ void k_wconv(const float* __restrict__ W_proj, u16* __restrict__ Wp)
{
    int gid = blockIdx.x * blockDim.x + threadIdx.x;  // 2 elems/thread
    int idx2 = gid * 2;
    if (idx2 >= V_PAD * D_IN) return;
    int row = idx2 >> 9;
    ushort2 w;
    if (row < V_DIM) {
        w.x = f2bf(W_proj[idx2]);
        w.y = f2bf(W_proj[idx2 + 1]);
    } else { w.x = 0; w.y = 0; }
    *(ushort2*)&Wp[idx2] = w;
}

// ---------------------------------------------------------------------------
// Kernel 3: joint[m,i] = tanh(enc[b,t,i] + dec[b,u,i]) -> bf16 [24064,512]
// one block per row, pad rows zeroed
// ---------------------------------------------------------------------------
__global__ void k_joint(const float* __restrict__ enc_o, const float* __restrict__ dec_o,
                        u16* __restrict__ J)
{
    int m = blockIdx.x;
    int i = threadIdx.x * 2;
    ushort2 w;
    if (m < M_TOT) {
        int b = m / (T_DIM * U_DIM);
        int r = m % (T_DIM * U_DIM);
        int t = r / U_DIM, u = r % U_DIM;
        const float* e = enc_o + (size_t)(b * T_DIM + t) * D_IN + i;
        const float* d = dec_o + (size_t)(b * U_DIM + u) * D_IN + i;
        w.x = f2bf(tanhf(e[0] + d[0]));
        w.y = f2bf(tanhf(e[1] + d[1]));
    } else { w.x = 0; w.y = 0; }
    *(ushort2*)&J[(size_t)m * D_IN + i] = w;
}

// ---------------------------------------------------------------------------
// Kernel 4: logits = J @ Wp^T + b_proj  -> d_out; per-row sum(exp) via atomics
// m97 structure: 128x128 tile, BK=32, 4 waves, 16x16x32 bf16 MFMA, 4x4/wave,
// global_load_lds width=16 staging.
// ---------------------------------------------------------------------------
__global__ __launch_bounds__(256, 2) void k_gemm(const u16* __restrict__ A,   // [M_PAD,512]
                                                 const u16* __restrict__ Bt,  // [V_PAD,512]
                                                 const float* __restrict__ bias,
                                                 float* __restrict__ C,       // [24000,4000]
                                                 float* __restrict__ sumexp)  // [24000]
{
    __shared__ u16 Ash[128 * 32];
    __shared__ u16 Bsh[128 * 32];
    const int row0 = blockIdx.x * 128;
    const int col0 = blockIdx.y * 128;
    const int tid  = threadIdx.x;
    const int wave = tid >> 6;
    const int lane = tid & 63;
    const int wm = wave >> 1, wn = wave & 1;    // 2x2 wave quadrants of 64x64
    const int lrow = lane & 15;                 // frag row/col-in-tile
    const int lq   = lane >> 4;                 // 0..3
    const int srow = lane >> 2;                 // staging: row within 16-row chunk
    const int scol = (lane & 3) * 8;            // staging: k elem offset

    floatx4 acc[4][4] = {};

    for (int k0 = 0; k0 < D_IN; k0 += 32) {
        __syncthreads();
        #pragma unroll
        for (int s = 0; s < 2; ++s) {
            int c = wave * 2 + s;               // 16-row chunk 0..7
            gld_lds16(A  + (size_t)(row0 + c * 16 + srow) * D_IN + k0 + scol, &Ash[c * 16 * 32]);
            gld_lds16(Bt + (size_t)(col0 + c * 16 + srow) * D_IN + k0 + scol, &Bsh[c * 16 * 32]);
        }
        __syncthreads();
        short8 af[4], bf[4];
        #pragma unroll
        for (int mi = 0; mi < 4; ++mi)
            af[mi] = *(const short8*)&Ash[(wm * 64 + mi * 16 + lrow) * 32 + lq * 8];
        #pragma unroll
        for (int nj = 0; nj < 4; ++nj)
            bf[nj] = *(const short8*)&Bsh[(wn * 64 + nj * 16 + lrow) * 32 + lq * 8];
        #pragma unroll
        for (int mi = 0; mi < 4; ++mi)
            #pragma unroll
            for (int nj = 0; nj < 4; ++nj)
                acc[mi][nj] = __builtin_amdgcn_mfma_f32_16x16x32_bf16(af[mi], bf[nj], acc[mi][nj], 0, 0, 0);
    }

    // epilogue: bias, store logits, per-row partial sum(exp) -> atomicAdd
    const int cbase = col0 + wn * 64;
    const int rbase = row0 + wm * 64;
    float bv[4];
    #pragma unroll
    for (int nj = 0; nj < 4; ++nj) {
        int cc = cbase + nj * 16 + lrow;
        bv[nj] = (cc < V_DIM) ? bias[cc] : 0.f;
    }
    #pragma unroll
    for (int mi = 0; mi < 4; ++mi) {
        float se[4] = {0.f, 0.f, 0.f, 0.f};
        #pragma unroll
        for (int nj = 0; nj < 4; ++nj) {
            int cc = cbase + nj * 16 + lrow;
            bool cok = (cc < V_DIM);
            #pragma unroll
            for (int r = 0; r < 4; ++r) {
                float logit = acc[mi][nj][r] + bv[nj];
                int rr = rbase + mi * 16 + lq * 4 + r;   // C/D: col=lane&15, row=(lane>>4)*4+reg
                if (cok) {
                    if (rr < M_TOT) C[(size_t)rr * V_DIM + cc] = logit;
                    se[r] += __expf(logit);
                }
            }
        }
        #pragma unroll
        for (int msk = 1; msk < 16; msk <<= 1) {
            #pragma unroll
            for (int r = 0; r < 4; ++r) se[r] += __shfl_xor(se[r], msk, 64);
        }
        if (lrow == 0) {
            #pragma unroll
            for (int r = 0; r < 4; ++r) {
                int rr = rbase + mi * 16 + lq * 4 + r;
                if (rr < M_TOT) atomicAdd(&sumexp[rr], se[r]);
            }
        }
    }
}

// ---------------------------------------------------------------------------
// Kernel 5: out[m,v] -= log(sumexp[m])   (float4 streaming)
// ---------------------------------------------------------------------------
__global__ void k_lse(float* __restrict__ C, const float* __restrict__ sumexp)
{
    int gid = blockIdx.x * blockDim.x + threadIdx.x;
    if (gid >= M_TOT * (V_DIM / 4)) return;
    int row = gid / (V_DIM / 4);
    float lse = __logf(sumexp[row]);
    float4 v = *((const float4*)C + gid);
    v.x -= lse; v.y -= lse; v.z -= lse; v.w -= lse;
    *((float4*)C + gid) = v;
}

extern "C" void kernel_launch(void* const* d_in, const int* in_sizes, int n_in,
                              void* d_out, int out_size, void* d_ws, size_t ws_size,
                              hipStream_t stream)
{
    const float* enc_state = (const float*)d_in[0];
    const float* dec_state = (const float*)d_in[1];
    const float* W_enc     = (const float*)d_in[2];
    const float* b_enc     = (const float*)d_in[3];
    const float* W_prd     = (const float*)d_in[4];
    const float* b_prd     = (const float*)d_in[5];
    const float* W_proj    = (const float*)d_in[6];
    const float* b_proj    = (const float*)d_in[7];
    float* out = (float*)d_out;

    char* ws = (char*)d_ws;
    float* sumexp = (float*)(ws);                 //     96,000 B (pad 102,400)
    float* enc_o  = (float*)(ws + 102400);        //  1,228,800 B
    float* dec_o  = (float*)(ws + 1331200);       //    327,680 B
    u16*   Wp     = (u16*)  (ws + 1658880);       //  4,194,304 B
    u16*   J      = (u16*)  (ws + 5853184);       // 24,641,536 B  (total ~30.5 MB)

    k_pre  <<<dim3(8, 24),   256, 0, stream>>>(enc_state, dec_state, W_enc, b_enc, W_prd, b_prd, enc_o, dec_o, sumexp);
    k_wconv<<<dim3(4096),    256, 0, stream>>>(W_proj, Wp);
    k_joint<<<dim3(M_PAD),   256, 0, stream>>>(enc_o, dec_o, J);
    k_gemm <<<dim3(188, 32), 256, 0, stream>>>(J, Wp, b_proj, out, sumexp);
    k_lse  <<<dim3(93750),   256, 0, stream>>>(out, sumexp);
}